// Round 4
// baseline (184.884 us; speedup 1.0000x reference)
//
#include <hip/hip_runtime.h>
#include <hip/hip_bf16.h>
#include <cstdint>

// Problem constants (B=2, S=2048, DIM=1024, H=16, KVH=4, HD=64, WINDOW=256)
#define S_LEN 2048
#define QKV_COLS 1536   // 1024 q | 256 k | 256 v

typedef __bf16 bf16_t;
typedef bf16_t bf16x8 __attribute__((ext_vector_type(8)));
typedef bf16_t bf16x4 __attribute__((ext_vector_type(4)));
typedef float f32x4 __attribute__((ext_vector_type(4)));

typedef __attribute__((address_space(1))) void as1_void;
typedef __attribute__((address_space(3))) void as3_void;

__device__ __forceinline__ void async_load16(const void* g, void* lds) {
  __builtin_amdgcn_global_load_lds(
      (as1_void*)(uintptr_t)g,
      (as3_void*)(uint32_t)(uintptr_t)lds,
      16, 0, 0);
}

// ---------------- f32 -> bf16 conversion of x, Wq|Wk|Wv (concat), Wo ---------
__global__ __launch_bounds__(256) void convert_all(
    const float4* __restrict__ x, const float4* __restrict__ wq,
    const float4* __restrict__ wk, const float4* __restrict__ wv,
    const float4* __restrict__ wo,
    bf16x4* __restrict__ xb, bf16x4* __restrict__ wqkvb, bf16x4* __restrict__ wob) {
  int u = blockIdx.x * 256 + threadIdx.x;
  const float4* src; bf16x4* dst; int off;
  if (u < 1048576)      { src = x;  dst = xb;            off = u; }
  else if (u < 1310720) { src = wq; dst = wqkvb;         off = u - 1048576; }
  else if (u < 1376256) { src = wk; dst = wqkvb + 262144; off = u - 1310720; }
  else if (u < 1441792) { src = wv; dst = wqkvb + 327680; off = u - 1376256; }
  else                  { src = wo; dst = wob;            off = u - 1441792; }
  float4 f = src[off];
  bf16x4 o;
  o[0] = (bf16_t)f.x; o[1] = (bf16_t)f.y; o[2] = (bf16_t)f.z; o[3] = (bf16_t)f.w;
  dst[off] = o;
}

// ---------------- QKV GEMM + fused RMSNorm/RoPE/gain + V-transpose ----------
// C[M,1536] = A[M,1024] * B[1536,1024]^T.
// q/k heads (cols<1280): RMSNorm + RoPE (+gain*0.125 for q) on f32 accs -> C.
// v heads (cols>=1280): write TRANSPOSED into vt[(b*4+g)*64+dh][s] (C skipped).
__global__ __launch_bounds__(256) void gemm_qkv(
    const bf16_t* __restrict__ A, const bf16_t* __restrict__ B,
    bf16_t* __restrict__ C, bf16_t* __restrict__ vt,
    const float* __restrict__ q_gain, int N, int K) {
  __shared__ bf16_t As[128 * 32];
  __shared__ bf16_t Bs[128 * 32];
  const int tid = threadIdx.x;
  const int lane = tid & 63;
  const int w = tid >> 6;
  const int wm = (w & 1) << 6, wn = (w >> 1) << 6;
  const int m0 = blockIdx.y << 7, n0 = blockIdx.x << 7;
  const int fidx = lane & 15, quad = lane >> 4;
  f32x4 acc[4][4] = {};
  const int c0 = tid, c1 = tid + 256;
  const bf16_t* Ag0 = A + (size_t)(m0 + (c0 >> 2)) * K + (c0 & 3) * 8;
  const bf16_t* Ag1 = A + (size_t)(m0 + (c1 >> 2)) * K + (c1 & 3) * 8;
  const bf16_t* Bg0 = B + (size_t)(n0 + (c0 >> 2)) * K + (c0 & 3) * 8;
  const bf16_t* Bg1 = B + (size_t)(n0 + (c1 >> 2)) * K + (c1 & 3) * 8;
  for (int kt = 0; kt < K; kt += 32) {
    __syncthreads();
    async_load16(Ag0 + kt, As + c0 * 8);
    async_load16(Ag1 + kt, As + c1 * 8);
    async_load16(Bg0 + kt, Bs + c0 * 8);
    async_load16(Bg1 + kt, Bs + c1 * 8);
    __syncthreads();
    bf16x8 af[4], bfr[4];
#pragma unroll
    for (int i = 0; i < 4; i++)
      af[i] = *(const bf16x8*)(As + (wm + i * 16 + fidx) * 32 + quad * 8);
#pragma unroll
    for (int i = 0; i < 4; i++)
      bfr[i] = *(const bf16x8*)(Bs + (wn + i * 16 + fidx) * 32 + quad * 8);
#pragma unroll
    for (int mi = 0; mi < 4; mi++)
#pragma unroll
      for (int ni = 0; ni < 4; ni++)
        acc[mi][ni] = __builtin_amdgcn_mfma_f32_16x16x32_bf16(
            af[mi], bfr[ni], acc[mi][ni], 0, 0, 0);
  }
  const int hc0 = n0 + wn;        // head starting col (multiple of 64)
  if (hc0 >= 1280) {
    // ---- V: transposed store. col c -> (g, dh); rows are tokens.
#pragma unroll
    for (int mi = 0; mi < 4; mi++)
#pragma unroll
      for (int ni = 0; ni < 4; ni++) {
        int cg = (hc0 - 1280) + ni * 16 + fidx;   // 0..255
        int g = cg >> 6, dh = cg & 63;
        int srow = m0 + wm + mi * 16 + quad * 4;  // first of 4 consecutive tokens
        int bb = srow >> 11, si = srow & (S_LEN - 1);
        bf16x4 pack;
#pragma unroll
        for (int r = 0; r < 4; r++) pack[r] = (bf16_t)acc[mi][ni][r];
        *(bf16x4*)(vt + ((size_t)((bb * 4 + g) * 64 + dh)) * S_LEN + si) = pack;
      }
    return;
  }
  // ---- q/k: RMSNorm + RoPE (+gain)
  float gain = 1.f;
  if (hc0 < 1024) gain = q_gain[hc0 >> 6] * 0.125f;  // fold softmax scale
#pragma unroll
  for (int mi = 0; mi < 4; mi++)
#pragma unroll
    for (int r = 0; r < 4; r++) {
      float ss = 0.f;
#pragma unroll
      for (int ni = 0; ni < 4; ni++) { float t = acc[mi][ni][r]; ss += t * t; }
#pragma unroll
      for (int off = 8; off >= 1; off >>= 1) ss += __shfl_xor(ss, off);
      float scl = rsqrtf(ss * (1.f / 64.f) + 1e-6f);
      int s = (m0 + wm + mi * 16 + quad * 4 + r) & (S_LEN - 1);
#pragma unroll
      for (int ni = 0; ni < 2; ni++) {
        float v1 = acc[mi][ni][r] * scl;
        float v2 = acc[mi][ni + 2][r] * scl;
        float fr = (float)(ni * 16 + fidx);
        float ang = (float)s * __expf(fr * -0.28782313662425575f);  // ln(1e4)/32
        float sn, cs;
        __sincosf(ang, &sn, &cs);
        acc[mi][ni][r]     = (v1 * cs + v2 * sn) * gain;
        acc[mi][ni + 2][r] = (-v1 * sn + v2 * cs) * gain;
      }
    }
#pragma unroll
  for (int mi = 0; mi < 4; mi++)
#pragma unroll
    for (int ni = 0; ni < 4; ni++)
#pragma unroll
      for (int r = 0; r < 4; r++) {
        int gr = m0 + wm + mi * 16 + quad * 4 + r;
        int gc = n0 + wn + ni * 16 + fidx;
        C[(size_t)gr * N + gc] = (bf16_t)acc[mi][ni][r];
      }
}

// ---------------- bf16 MFMA GEMM (f32 out): C = A * B^T ---------------------
__global__ __launch_bounds__(256) void gemm_bt_f32(
    const bf16_t* __restrict__ A, const bf16_t* __restrict__ B,
    float* __restrict__ C, int N, int K) {
  __shared__ bf16_t As[128 * 32];
  __shared__ bf16_t Bs[128 * 32];
  const int tid = threadIdx.x;
  const int lane = tid & 63;
  const int w = tid >> 6;
  const int wm = (w & 1) << 6, wn = (w >> 1) << 6;
  const int m0 = blockIdx.y << 7, n0 = blockIdx.x << 7;
  const int fidx = lane & 15, quad = lane >> 4;
  f32x4 acc[4][4] = {};
  const int c0 = tid, c1 = tid + 256;
  const bf16_t* Ag0 = A + (size_t)(m0 + (c0 >> 2)) * K + (c0 & 3) * 8;
  const bf16_t* Ag1 = A + (size_t)(m0 + (c1 >> 2)) * K + (c1 & 3) * 8;
  const bf16_t* Bg0 = B + (size_t)(n0 + (c0 >> 2)) * K + (c0 & 3) * 8;
  const bf16_t* Bg1 = B + (size_t)(n0 + (c1 >> 2)) * K + (c1 & 3) * 8;
  for (int kt = 0; kt < K; kt += 32) {
    __syncthreads();
    async_load16(Ag0 + kt, As + c0 * 8);
    async_load16(Ag1 + kt, As + c1 * 8);
    async_load16(Bg0 + kt, Bs + c0 * 8);
    async_load16(Bg1 + kt, Bs + c1 * 8);
    __syncthreads();
    bf16x8 af[4], bfr[4];
#pragma unroll
    for (int i = 0; i < 4; i++)
      af[i] = *(const bf16x8*)(As + (wm + i * 16 + fidx) * 32 + quad * 8);
#pragma unroll
    for (int i = 0; i < 4; i++)
      bfr[i] = *(const bf16x8*)(Bs + (wn + i * 16 + fidx) * 32 + quad * 8);
#pragma unroll
    for (int mi = 0; mi < 4; mi++)
#pragma unroll
      for (int ni = 0; ni < 4; ni++)
        acc[mi][ni] = __builtin_amdgcn_mfma_f32_16x16x32_bf16(
            af[mi], bfr[ni], acc[mi][ni], 0, 0, 0);
  }
#pragma unroll
  for (int mi = 0; mi < 4; mi++)
#pragma unroll
    for (int ni = 0; ni < 4; ni++)
#pragma unroll
      for (int r = 0; r < 4; r++) {
        int gr = m0 + wm + mi * 16 + quad * 4 + r;
        int gc = n0 + wn + ni * 16 + fidx;
        C[(size_t)gr * N + gc] = acc[mi][ni][r];
      }
}

// ---------------- MFMA flash attention + pair mix ---------------------------
// block = (b, kvh group g, 16-query tile). 4 waves = 4 q heads of the group.
// 64-key chunks; interior chunks skip all mask VALU (wave-uniform test).
// 1024 blocks -> 4 blocks/CU, 16 waves/CU.
#define PST 72  // P row stride (bf16): col*144B keeps b128 16B-aligned; 2-way bank alias only
__global__ __launch_bounds__(256, 4) void attn_mfma(
    const bf16_t* __restrict__ qkv, const bf16_t* __restrict__ vt,
    const float* __restrict__ pair_mix, bf16_t* __restrict__ yb) {
  __shared__ bf16_t plds[4][16 * PST];
  __shared__ float olds[4][16][64];
  const int tid = threadIdx.x, lane = tid & 63, w = tid >> 6;
  const int col = lane & 15, quad = lane >> 4;
  const int q0 = blockIdx.x * 16, g = blockIdx.y, b = blockIdx.z;
  const int h = g * 4 + w;

  const bf16_t* qb = qkv + ((size_t)b * S_LEN + q0 + col) * QKV_COLS + h * 64 + quad * 8;
  bf16x8 qf0 = *(const bf16x8*)qb;
  bf16x8 qf1 = *(const bf16x8*)(qb + 32);

  const bf16_t* kbase = qkv + (size_t)b * S_LEN * QKV_COLS + 1024 + g * 64 + quad * 8;
  const bf16_t* vbase = vt + ((size_t)((b * 4 + g) * 64) + col) * S_LEN + quad * 8;

  f32x4 o[4] = {};
  float m[4], l[4];
#pragma unroll
  for (int r = 0; r < 4; r++) { m[r] = -1e30f; l[r] = 0.f; }

  const int c_lo = max(0, (q0 - 255) >> 6);
  const int c_hi = (q0 + 15) >> 6;
  for (int c = c_lo; c <= c_hi; c++) {
    const int k0 = c * 64;
    // ---- scores S[16q x 64k]: 4 N-tiles x 2 Kdim-halves
    f32x4 s4[4];
#pragma unroll
    for (int nt = 0; nt < 4; nt++) {
      const bf16_t* kp = kbase + (size_t)(k0 + nt * 16 + col) * QKV_COLS;
      bf16x8 kf0 = *(const bf16x8*)kp;
      bf16x8 kf1 = *(const bf16x8*)(kp + 32);
      f32x4 a = {};
      a = __builtin_amdgcn_mfma_f32_16x16x32_bf16(qf0, kf0, a, 0, 0, 0);
      a = __builtin_amdgcn_mfma_f32_16x16x32_bf16(qf1, kf1, a, 0, 0, 0);
      s4[nt] = a;
    }
    const bool needmask = (k0 + 63 > q0) || (k0 < q0 - 240);  // wave-uniform
    float alpha[4], psum[4];
    if (needmask) {
#pragma unroll
      for (int r = 0; r < 4; r++) {
        int q = q0 + quad * 4 + r;
#pragma unroll
        for (int nt = 0; nt < 4; nt++) {
          int k = k0 + nt * 16 + col;
          bool valid = (k <= q) && (q - k < 256);
          s4[nt][r] = valid ? s4[nt][r] : -1e30f;
        }
        float v = fmaxf(fmaxf(s4[0][r], s4[1][r]), fmaxf(s4[2][r], s4[3][r]));
#pragma unroll
        for (int off = 8; off >= 1; off >>= 1) v = fmaxf(v, __shfl_xor(v, off));
        float mn = fmaxf(m[r], v);
        alpha[r] = __expf(m[r] - mn);
        m[r] = mn;
        float ps = 0.f;
#pragma unroll
        for (int nt = 0; nt < 4; nt++) {
          float sv = s4[nt][r];
          float p = (sv > -1e29f) ? __expf(sv - m[r]) : 0.f;
          ps += p;
          plds[w][(quad * 4 + r) * PST + nt * 16 + col] = (bf16_t)p;
        }
        psum[r] = ps;
      }
    } else {
#pragma unroll
      for (int r = 0; r < 4; r++) {
        float v = fmaxf(fmaxf(s4[0][r], s4[1][r]), fmaxf(s4[2][r], s4[3][r]));
#pragma unroll
        for (int off = 8; off >= 1; off >>= 1) v = fmaxf(v, __shfl_xor(v, off));
        float mn = fmaxf(m[r], v);
        alpha[r] = __expf(m[r] - mn);
        m[r] = mn;
        float ps = 0.f;
#pragma unroll
        for (int nt = 0; nt < 4; nt++) {
          float p = __expf(s4[nt][r] - m[r]);
          ps += p;
          plds[w][(quad * 4 + r) * PST + nt * 16 + col] = (bf16_t)p;
        }
        psum[r] = ps;
      }
    }
#pragma unroll
    for (int r = 0; r < 4; r++) {
      float v = psum[r];
#pragma unroll
      for (int off = 8; off >= 1; off >>= 1) v += __shfl_xor(v, off);
      l[r] = l[r] * alpha[r] + v;
#pragma unroll
      for (int nt2 = 0; nt2 < 4; nt2++) o[nt2][r] *= alpha[r];
    }
    // ---- PV: P A-frags from LDS (two K=32 halves) vs transposed V
    asm volatile("s_waitcnt lgkmcnt(0)" ::: "memory");
    bf16x8 pf0 = *(const bf16x8*)(plds[w] + col * PST + quad * 8);
    bf16x8 pf1 = *(const bf16x8*)(plds[w] + col * PST + 32 + quad * 8);
#pragma unroll
    for (int nt2 = 0; nt2 < 4; nt2++) {
      const bf16_t* vp = vbase + (size_t)(nt2 * 16) * S_LEN + k0;
      bf16x8 vf0 = *(const bf16x8*)vp;
      bf16x8 vf1 = *(const bf16x8*)(vp + 32);
      o[nt2] = __builtin_amdgcn_mfma_f32_16x16x32_bf16(pf0, vf0, o[nt2], 0, 0, 0);
      o[nt2] = __builtin_amdgcn_mfma_f32_16x16x32_bf16(pf1, vf1, o[nt2], 0, 0, 0);
    }
  }
#pragma unroll
  for (int r = 0; r < 4; r++) {
    float il = 1.f / l[r];
#pragma unroll
    for (int nt2 = 0; nt2 < 4; nt2++)
      olds[w][quad * 4 + r][nt2 * 16 + col] = o[nt2][r] * il;
  }
  __syncthreads();
  // ---- pair mix + coalesced bf16x8 writes (4096 outputs / block)
#pragma unroll
  for (int i = 0; i < 2; i++) {
    int chunk = tid * 2 + i;      // 0..511
    int tok = chunk >> 5;         // 0..15
    int cg = chunk & 31;
    int hh = cg >> 3;
    int d0 = (cg & 7) * 8;
    int p_loc = hh >> 1, oo = hh & 1;
    int wb = p_loc * 2;
    int hp = g * 2 + p_loc;
    float pm0 = pair_mix[hp * 4 + oo * 2 + 0];
    float pm1 = pair_mix[hp * 4 + oo * 2 + 1];
    bf16x8 outv;
#pragma unroll
    for (int j = 0; j < 8; j++)
      outv[j] = (bf16_t)(pm0 * olds[wb][tok][d0 + j] + pm1 * olds[wb + 1][tok][d0 + j]);
    *(bf16x8*)(yb + ((size_t)b * S_LEN + q0 + tok) * 1024 + (g * 4 + hh) * 64 + d0) = outv;
  }
}

extern "C" void kernel_launch(void* const* d_in, const int* in_sizes, int n_in,
                              void* d_out, int out_size, void* d_ws, size_t ws_size,
                              hipStream_t stream) {
  const float* x        = (const float*)d_in[0];
  const float* Wq       = (const float*)d_in[1];
  const float* Wk       = (const float*)d_in[2];
  const float* Wv       = (const float*)d_in[3];
  const float* Wo       = (const float*)d_in[4];
  const float* q_gain   = (const float*)d_in[5];
  const float* pair_mix = (const float*)d_in[6];
  float* out = (float*)d_out;

  bf16_t* ws    = (bf16_t*)d_ws;
  bf16_t* xb    = ws;                   // 4096*1024
  bf16_t* wqkvb = xb + 4096 * 1024;     // 1536*1024
  bf16_t* wob   = wqkvb + 1536 * 1024;  // 1024*1024
  bf16_t* qkvb  = wob + 1024 * 1024;    // 4096*1536
  bf16_t* yb    = qkvb + 4096 * 1536;   // 4096*1024
  bf16_t* vt    = yb + 4096 * 1024;     // 8*64*2048 (total ~36.7 MB; ws is ~268 MB)

  convert_all<<<6656, 256, 0, stream>>>(
      (const float4*)x, (const float4*)Wq, (const float4*)Wk, (const float4*)Wv,
      (const float4*)Wo, (bf16x4*)xb, (bf16x4*)wqkvb, (bf16x4*)wob);
  gemm_qkv<<<dim3(12, 32), 256, 0, stream>>>(xb, wqkvb, qkvb, vt, q_gain, 1536, 1024);
  attn_mfma<<<dim3(128, 4, 2), 256, 0, stream>>>(qkvb, vt, pair_mix, yb);
  gemm_bt_f32<<<dim3(8, 32), 256, 0, stream>>>(yb, wob, out, 1024, 1024);
}